// Round 19
// baseline (76.724 us; speedup 1.0000x reference)
//
#include <hip/hip_runtime.h>
#include <math.h>

#ifndef M_PI
#define M_PI 3.14159265358979323846
#endif

#define NFILT   10
#define THREADS 1024
#define CHUNK   64                  // per thread: .x = samples [0,32), .y = [32,64)
#define LTOT    (THREADS * CHUNK)   // 65536
#define NWAVE   (THREADS / 64)      // 16

#define WS_STRIDE 576               // floats per batch
#define MATS_OFF  96                // coefs: j*8; matrices: j*44 + r*4 (r=0..9 = C^(64*2^r), r=10 = C^32)

typedef float v2f __attribute__((ext_vector_type(2)));
__device__ inline v2f mk2(float a, float b) { v2f r; r.x = a; r.y = b; return r; }
__device__ inline v2f fs(float s) { return mk2(s, s); }
#define F2(a,b,c) __builtin_elementwise_fma((a),(b),(c))

// ---------------- precompute (f64) ----------------

__device__ inline void biquad_coefs(int k, double w0r, double qir, double gr,
                                    double* bo, double* ao) {
    const double w0 = M_PI / (1.0 + exp(-w0r));
    const double qi = exp(qir);
    const double A  = exp(gr);
    const double cw = cos(w0);
    const double al = sin(w0) * qi * 0.5;
    double B0, B1, B2, A0, A1, A2;
    if (k == 0) {
        const double Ap1 = A + 1.0, Am1 = A - 1.0, tsa = 2.0 * sqrt(A) * al;
        B0 = A * (Ap1 - Am1 * cw + tsa);
        B1 = 2.0 * A * (Am1 - Ap1 * cw);
        B2 = A * (Ap1 - Am1 * cw - tsa);
        A0 = Ap1 + Am1 * cw + tsa;
        A1 = -2.0 * (Am1 + Ap1 * cw);
        A2 = Ap1 + Am1 * cw - tsa;
    } else if (k == NFILT - 1) {
        const double Ap1 = A + 1.0, Am1 = A - 1.0, tsa = 2.0 * sqrt(A) * al;
        B0 = A * (Ap1 + Am1 * cw + tsa);
        B1 = -2.0 * A * (Am1 + Ap1 * cw);
        B2 = A * (Ap1 + Am1 * cw - tsa);
        A0 = Ap1 - Am1 * cw + tsa;
        A1 = 2.0 * (Am1 - Ap1 * cw);
        A2 = Ap1 - Am1 * cw - tsa;
    } else {
        const double aA = al * A, aiA = al / A;
        B0 = 1.0 + aA;  B1 = -2.0 * cw; B2 = 1.0 - aA;
        A0 = 1.0 + aiA; A1 = B1;        A2 = 1.0 - aiA;
    }
    const double inv = 1.0 / A0;
    bo[0] = B0 * inv; bo[1] = B1 * inv; bo[2] = B2 * inv;
    ao[0] = 1.0;      ao[1] = A1 * inv; ao[2] = A2 * inv;
}

__global__ void eq_precompute_kernel(const float* __restrict__ w0_in,
                                     const float* __restrict__ qinv_in,
                                     const float* __restrict__ gain_in,
                                     float* __restrict__ ws)
{
    const int b = blockIdx.x;
    const int j = threadIdx.x;
    if (j >= NFILT) return;

    double bo[3], ao[3];
    biquad_coefs(j, (double)w0_in[b*NFILT+j], (double)qinv_in[b*NFILT+j],
                 (double)gain_in[b*NFILT+j], bo, ao);

    float* wb = ws + (size_t)b * WS_STRIDE;
    float* cj = wb + j * 8;
    cj[0] = (float)bo[0]; cj[1] = (float)bo[1]; cj[2] = (float)bo[2];
    cj[3] = (float)ao[1]; cj[4] = (float)ao[2];

    double m0 = -ao[1], m1 = -ao[2], m2 = 1.0, m3 = 0.0;   // C
    #pragma unroll
    for (int i = 0; i < 5; ++i) {                          // -> C^32
        const double n0 = m0*m0 + m1*m2, n1 = m0*m1 + m1*m3;
        const double n2 = m2*m0 + m3*m2, n3 = m2*m1 + m3*m3;
        m0 = n0; m1 = n1; m2 = n2; m3 = n3;
    }
    {   // slot 10 = C^32
        float* mr = wb + MATS_OFF + j*44 + 10*4;
        mr[0] = (float)m0; mr[1] = (float)m1; mr[2] = (float)m2; mr[3] = (float)m3;
    }
    {   // -> C^64
        const double n0 = m0*m0 + m1*m2, n1 = m0*m1 + m1*m3;
        const double n2 = m2*m0 + m3*m2, n3 = m2*m1 + m3*m3;
        m0 = n0; m1 = n1; m2 = n2; m3 = n3;
    }
    for (int r = 0; r < 10; ++r) {                         // C^(64*2^r)
        float* mr = wb + MATS_OFF + j*44 + r*4;
        mr[0] = (float)m0; mr[1] = (float)m1; mr[2] = (float)m2; mr[3] = (float)m3;
        const double n0 = m0*m0 + m1*m2, n1 = m0*m1 + m1*m3;
        const double n2 = m2*m0 + m3*m2, n3 = m2*m1 + m3*m3;
        m0 = n0; m1 = n1; m2 = n2; m3 = n3;
    }
}

// ---------------- main kernel ----------------

__global__ void
__attribute__((amdgpu_flat_work_group_size(THREADS, THREADS)))
__attribute__((amdgpu_waves_per_eu(4, 4)))
eq_cascade_kernel(const float* __restrict__ x,
                  float* __restrict__ out,
                  const float* __restrict__ ws)
{
    __shared__ float4 sigh[8][THREADS];   // v2f sample pairs s=16..31, 128 KiB, thread-private
    __shared__ float2 bnd[THREADS];       // per-thread raw tail (x[63], x[62])
    __shared__ float2 waveP[2][NWAVE];

    const int tid  = threadIdx.x;
    const int lane = tid & 63;
    const int wid  = tid >> 6;
    const int b    = blockIdx.x;
    const float* __restrict__ wsb = ws + (size_t)b * WS_STRIDE;

    const float* xb = x   + (size_t)b * LTOT;
    float*       ob = out + (size_t)b * LTOT;

    v2f sig[16];   // s=0..15: .x = sample s, .y = sample 32+s

    // ---- load 64 samples, FUSED (max 2 float4 live -> no prologue spill) ----
    const float4* src = reinterpret_cast<const float4*>(xb + (size_t)tid * CHUNK);
    float xty1, xty2;
    #pragma unroll
    for (int i = 0; i < 4; ++i) {        // s=4i..4i+3 -> registers
        const float4 a = src[i];
        const float4 c = src[8 + i];
        sig[4*i+0] = mk2(a.x, c.x); sig[4*i+1] = mk2(a.y, c.y);
        sig[4*i+2] = mk2(a.z, c.z); sig[4*i+3] = mk2(a.w, c.w);
    }
    #pragma unroll
    for (int i = 4; i < 8; ++i) {        // s=16..31 -> LDS (pairs)
        const float4 a = src[i];
        const float4 c = src[8 + i];
        sigh[2*(i-4)][tid]   = make_float4(a.x, c.x, a.y, c.y);
        sigh[2*(i-4)+1][tid] = make_float4(a.z, c.z, a.w, c.w);
        if (i == 7) {
            xty1 = a.w; xty2 = a.z;                 // own .x tail = .y raw history
            bnd[tid] = make_float2(c.w, c.z);       // thread raw tail (sample 63, 62)
        }
    }
    __syncthreads();

    v2f xw1, xw2;   // raw-x history per stream
    {
        float h1 = 0.f, h2 = 0.f;
        if (tid > 0) { const float2 t = bnd[tid-1]; h1 = t.x; h2 = t.y; }
        xw1 = mk2(h1, xty1);
        xw2 = mk2(h2, xty2);
    }

    v2f i1 = mk2(0.f,0.f), i2 = mk2(0.f,0.f);
    float pa1 = 0.f, pa2 = 0.f;

    #pragma unroll 1
    for (int j = 0; j < NFILT; ++j) {
        const float* cj = wsb + j*8;
        const float b0 = cj[0], b1c = cj[1], b2 = cj[2], a1 = cj[3], a2 = cj[4];
        const float* mb = wsb + MATS_OFF + j*44;
        const v2f nb0 = fs(b0), nb1 = fs(b1c), nb2 = fs(b2);
        const v2f na1 = fs(-a1), na2 = fs(-a2);
        const v2f np1 = fs(-pa1), np2 = fs(-pa2);

        // ---- fused elementwise: finalize(j-1) + FIR(j) + zero-init(j) ----
        v2f u1, u2, z1 = mk2(0.f,0.f), z2 = mk2(0.f,0.f);
        if (j == 0) { u1 = xw1; u2 = xw2; } else { u1 = i1; u2 = i2; }

        if (j == 0) {
            #pragma unroll
            for (int t = 0; t < 16; ++t) {
                const v2f u = sig[t];
                const v2f c = F2(nb0, u, F2(nb1, u1, nb2*u2));
                const v2f z = F2(na1, z1, F2(na2, z2, c));
                sig[t] = c; u2 = u1; u1 = u; z2 = z1; z1 = z;
            }
            #pragma unroll
            for (int i = 0; i < 8; ++i) {
                const float4 v = sigh[i][tid];
                v2f p = mk2(v.x, v.y), q = mk2(v.z, v.w);
                {
                    const v2f u = p;
                    const v2f c = F2(nb0, u, F2(nb1, u1, nb2*u2));
                    const v2f z = F2(na1, z1, F2(na2, z2, c));
                    p = c; u2 = u1; u1 = u; z2 = z1; z1 = z;
                }
                {
                    const v2f u = q;
                    const v2f c = F2(nb0, u, F2(nb1, u1, nb2*u2));
                    const v2f z = F2(na1, z1, F2(na2, z2, c));
                    q = c; u2 = u1; u1 = u; z2 = z1; z1 = z;
                }
                sigh[i][tid] = make_float4(p.x, p.y, q.x, q.y);
            }
        } else {
            #pragma unroll
            for (int t = 0; t < 16; ++t) {
                const v2f u = F2(np1, u1, F2(np2, u2, sig[t]));
                const v2f c = F2(nb0, u, F2(nb1, u1, nb2*u2));
                const v2f z = F2(na1, z1, F2(na2, z2, c));
                sig[t] = c; u2 = u1; u1 = u; z2 = z1; z1 = z;
            }
            #pragma unroll
            for (int i = 0; i < 8; ++i) {
                const float4 v = sigh[i][tid];
                v2f p = mk2(v.x, v.y), q = mk2(v.z, v.w);
                {
                    const v2f u = F2(np1, u1, F2(np2, u2, p));
                    const v2f c = F2(nb0, u, F2(nb1, u1, nb2*u2));
                    const v2f z = F2(na1, z1, F2(na2, z2, c));
                    p = c; u2 = u1; u1 = u; z2 = z1; z1 = z;
                }
                {
                    const v2f u = F2(np1, u1, F2(np2, u2, q));
                    const v2f c = F2(nb0, u, F2(nb1, u1, nb2*u2));
                    const v2f z = F2(na1, z1, F2(na2, z2, c));
                    q = c; u2 = u1; u1 = u; z2 = z1; z1 = z;
                }
                sigh[i][tid] = make_float4(p.x, p.y, q.x, q.y);
            }
        }

        // ---- thread particular over 64 samples: P = C^32 * z_x + z_y (scalar) ----
        const float4 M32 = *reinterpret_cast<const float4*>(mb + 10*4);
        float Sa = M32.x * z1.x + M32.y * z2.x + z1.y;
        float Sb = M32.z * z1.x + M32.w * z2.x + z2.y;

        // ---- in-wave inclusive affine scan (scalar, C^(64*2^r)) ----
        #pragma unroll
        for (int r = 0; r < 6; ++r) {
            const int d = 1 << r;
            const float4 M = *reinterpret_cast<const float4*>(mb + r*4);
            float ta = __shfl_up(Sa, d, 64);
            float tb = __shfl_up(Sb, d, 64);
            const bool act = (lane >= d);
            ta = act ? ta : 0.f;
            tb = act ? tb : 0.f;
            Sa = Sa + M.x * ta + M.y * tb;
            Sb = Sb + M.z * ta + M.w * tb;
        }
        const int buf = j & 1;
        if (lane == 63) waveP[buf][wid] = make_float2(Sa, Sb);
        __syncthreads();

        // ---- cross-wave: 4-level KS over 16 wave totals (lane space) ----
        const float2 Pv = waveP[buf][lane & 15];
        float Tx = Pv.x, Ty = Pv.y;
        #pragma unroll
        for (int l = 0; l < 4; ++l) {
            const int d = 1 << l;
            const float4 M = *reinterpret_cast<const float4*>(mb + (6+l)*4);
            float tx = __shfl_up(Tx, d, 64);
            float ty = __shfl_up(Ty, d, 64);
            const bool act = (lane >= d);
            tx = act ? tx : 0.f;
            ty = act ? ty : 0.f;
            Tx = Tx + M.x * tx + M.y * ty;
            Ty = Ty + M.z * tx + M.w * ty;
        }
        float Vx = __shfl(Tx, wid - 1, 64);
        float Vy = __shfl(Ty, wid - 1, 64);
        if (wid == 0) { Vx = 0.f; Vy = 0.f; }
        #pragma unroll
        for (int r = 0; r < 6; ++r) {      // apply C^(64*lane)
            const float4 M = *reinterpret_cast<const float4*>(mb + r*4);
            const bool bit = (lane >> r) & 1;
            const float nx = M.x * Vx + M.y * Vy;
            const float ny = M.z * Vx + M.w * Vy;
            Vx = bit ? nx : Vx;
            Vy = bit ? ny : Vy;
        }
        {   // + exclusive in-thread-space particular prefix
            float Ea = __shfl_up(Sa, 1, 64);
            float Eb = __shfl_up(Sb, 1, 64);
            const bool l0 = (lane == 0);
            Vx += l0 ? 0.f : Ea;
            Vy += l0 ? 0.f : Eb;
        }

        // ---- per-stream incoming states: .x gets V; .y gets C^32*V + z_x ----
        const float iy1 = M32.x * Vx + M32.y * Vy + z1.x;
        const float iy2 = M32.z * Vx + M32.w * Vy + z2.x;
        i1 = mk2(Vx, iy1);
        i2 = mk2(Vy, iy2);
        pa1 = a1; pa2 = a2;
    }

    // ---- tail: elementwise finalize of filter 9, de-interleave, store ----
    {
        v2f u1 = i1, u2 = i2;
        const v2f np1 = fs(-pa1), np2 = fs(-pa2);
        float4* d0 = reinterpret_cast<float4*>(ob + (size_t)tid * CHUNK);        // samples 0..31
        float4* d1 = reinterpret_cast<float4*>(ob + (size_t)tid * CHUNK + 32);   // samples 32..63
        #pragma unroll
        for (int i = 0; i < 4; ++i) {
            float4 a, c;
            #pragma unroll
            for (int e = 0; e < 4; ++e) {
                const v2f u = F2(np1, u1, F2(np2, u2, sig[4*i+e]));
                (&a.x)[e] = u.x; (&c.x)[e] = u.y;
                u2 = u1; u1 = u;
            }
            d0[i] = a; d1[i] = c;
        }
        #pragma unroll
        for (int i = 0; i < 4; ++i) {
            const float4 v = sigh[2*i][tid], w = sigh[2*i+1][tid];
            const v2f s0v = mk2(v.x, v.y), s1v = mk2(v.z, v.w);
            const v2f s2v = mk2(w.x, w.y), s3v = mk2(w.z, w.w);
            float4 a, c;
            v2f u;
            u = F2(np1, u1, F2(np2, u2, s0v)); a.x = u.x; c.x = u.y; u2 = u1; u1 = u;
            u = F2(np1, u1, F2(np2, u2, s1v)); a.y = u.x; c.y = u.y; u2 = u1; u1 = u;
            u = F2(np1, u1, F2(np2, u2, s2v)); a.z = u.x; c.z = u.y; u2 = u1; u1 = u;
            u = F2(np1, u1, F2(np2, u2, s3v)); a.w = u.x; c.w = u.y; u2 = u1; u1 = u;
            d0[4+i] = a; d1[4+i] = c;
        }
    }
}

extern "C" void kernel_launch(void* const* d_in, const int* in_sizes, int n_in,
                              void* d_out, int out_size, void* d_ws, size_t ws_size,
                              hipStream_t stream) {
    const float* x    = (const float*)d_in[0];
    const float* w0   = (const float*)d_in[1];
    const float* qinv = (const float*)d_in[2];
    const float* gain = (const float*)d_in[3];
    float* out = (float*)d_out;
    float* ws  = (float*)d_ws;   // 256 * 576 * 4 B = 576 KiB

    const int B = in_sizes[1] / NFILT;   // 256 batches
    eq_precompute_kernel<<<B, 64, 0, stream>>>(w0, qinv, gain, ws);
    eq_cascade_kernel<<<B, THREADS, 0, stream>>>(x, out, ws);
}

// Round 20
// 72.913 us; speedup vs baseline: 1.0523x; 1.0523x over previous
//
#include <hip/hip_runtime.h>
#include <math.h>

#ifndef M_PI
#define M_PI 3.14159265358979323846
#endif

#define NFILT   10
#define THREADS 1024
#define CHUNK   64                  // per thread: .x = samples [0,32), .y = [32,64)
#define LTOT    (THREADS * CHUNK)   // 65536
#define NWAVE   (THREADS / 64)      // 16

#define WS_STRIDE 576               // floats per batch
#define MATS_OFF  96                // coefs: j*8; matrices: j*44 + r*4 (r=0..9 = C^(64*2^r), r=10 = C^32)

typedef float v2f __attribute__((ext_vector_type(2)));
__device__ inline v2f mk2(float a, float b) { v2f r; r.x = a; r.y = b; return r; }
__device__ inline v2f fs(float s) { return mk2(s, s); }
#define F2(a,b,c) __builtin_elementwise_fma((a),(b),(c))

// ---------------- precompute (f64) ----------------

__device__ inline void biquad_coefs(int k, double w0r, double qir, double gr,
                                    double* bo, double* ao) {
    const double w0 = M_PI / (1.0 + exp(-w0r));
    const double qi = exp(qir);
    const double A  = exp(gr);
    const double cw = cos(w0);
    const double al = sin(w0) * qi * 0.5;
    double B0, B1, B2, A0, A1, A2;
    if (k == 0) {
        const double Ap1 = A + 1.0, Am1 = A - 1.0, tsa = 2.0 * sqrt(A) * al;
        B0 = A * (Ap1 - Am1 * cw + tsa);
        B1 = 2.0 * A * (Am1 - Ap1 * cw);
        B2 = A * (Ap1 - Am1 * cw - tsa);
        A0 = Ap1 + Am1 * cw + tsa;
        A1 = -2.0 * (Am1 + Ap1 * cw);
        A2 = Ap1 + Am1 * cw - tsa;
    } else if (k == NFILT - 1) {
        const double Ap1 = A + 1.0, Am1 = A - 1.0, tsa = 2.0 * sqrt(A) * al;
        B0 = A * (Ap1 + Am1 * cw + tsa);
        B1 = -2.0 * A * (Am1 + Ap1 * cw);
        B2 = A * (Ap1 + Am1 * cw - tsa);
        A0 = Ap1 - Am1 * cw + tsa;
        A1 = 2.0 * (Am1 - Ap1 * cw);
        A2 = Ap1 - Am1 * cw - tsa;
    } else {
        const double aA = al * A, aiA = al / A;
        B0 = 1.0 + aA;  B1 = -2.0 * cw; B2 = 1.0 - aA;
        A0 = 1.0 + aiA; A1 = B1;        A2 = 1.0 - aiA;
    }
    const double inv = 1.0 / A0;
    bo[0] = B0 * inv; bo[1] = B1 * inv; bo[2] = B2 * inv;
    ao[0] = 1.0;      ao[1] = A1 * inv; ao[2] = A2 * inv;
}

__global__ void eq_precompute_kernel(const float* __restrict__ w0_in,
                                     const float* __restrict__ qinv_in,
                                     const float* __restrict__ gain_in,
                                     float* __restrict__ ws)
{
    const int b = blockIdx.x;
    const int j = threadIdx.x;
    if (j >= NFILT) return;

    double bo[3], ao[3];
    biquad_coefs(j, (double)w0_in[b*NFILT+j], (double)qinv_in[b*NFILT+j],
                 (double)gain_in[b*NFILT+j], bo, ao);

    float* wb = ws + (size_t)b * WS_STRIDE;
    float* cj = wb + j * 8;
    cj[0] = (float)bo[0]; cj[1] = (float)bo[1]; cj[2] = (float)bo[2];
    cj[3] = (float)ao[1]; cj[4] = (float)ao[2];

    double m0 = -ao[1], m1 = -ao[2], m2 = 1.0, m3 = 0.0;   // C
    #pragma unroll
    for (int i = 0; i < 5; ++i) {                          // -> C^32
        const double n0 = m0*m0 + m1*m2, n1 = m0*m1 + m1*m3;
        const double n2 = m2*m0 + m3*m2, n3 = m2*m1 + m3*m3;
        m0 = n0; m1 = n1; m2 = n2; m3 = n3;
    }
    {   // slot 10 = C^32
        float* mr = wb + MATS_OFF + j*44 + 10*4;
        mr[0] = (float)m0; mr[1] = (float)m1; mr[2] = (float)m2; mr[3] = (float)m3;
    }
    {   // -> C^64
        const double n0 = m0*m0 + m1*m2, n1 = m0*m1 + m1*m3;
        const double n2 = m2*m0 + m3*m2, n3 = m2*m1 + m3*m3;
        m0 = n0; m1 = n1; m2 = n2; m3 = n3;
    }
    for (int r = 0; r < 10; ++r) {                         // C^(64*2^r)
        float* mr = wb + MATS_OFF + j*44 + r*4;
        mr[0] = (float)m0; mr[1] = (float)m1; mr[2] = (float)m2; mr[3] = (float)m3;
        const double n0 = m0*m0 + m1*m2, n1 = m0*m1 + m1*m3;
        const double n2 = m2*m0 + m3*m2, n3 = m2*m1 + m3*m3;
        m0 = n0; m1 = n1; m2 = n2; m3 = n3;
    }
}

// ---------------- main kernel ----------------

__global__ void
__attribute__((amdgpu_flat_work_group_size(THREADS, THREADS)))
__attribute__((amdgpu_waves_per_eu(4, 4)))
eq_cascade_kernel(const float* __restrict__ x,
                  float* __restrict__ out,
                  const float* __restrict__ ws)
{
    __shared__ float4 sigh[8][THREADS];   // v2f sample pairs s=16..31, 128 KiB, thread-private
    __shared__ float2 bnd[THREADS];       // per-thread raw tail (x[63], x[62])
    __shared__ float2 waveP[2][NWAVE];

    const int tid  = threadIdx.x;
    const int lane = tid & 63;
    const int wid  = tid >> 6;
    const int b    = blockIdx.x;
    const float* __restrict__ wsb = ws + (size_t)b * WS_STRIDE;

    const float* xb = x   + (size_t)b * LTOT;
    float*       ob = out + (size_t)b * LTOT;

    v2f sig[16];   // s=0..15: .x = sample s, .y = sample 32+s

    // ---- load 64 samples, fused (max 2 float4 live) ----
    const float4* src = reinterpret_cast<const float4*>(xb + (size_t)tid * CHUNK);
    float xty1, xty2;
    #pragma unroll
    for (int i = 0; i < 4; ++i) {        // s=4i..4i+3 -> registers
        const float4 a = src[i];
        const float4 c = src[8 + i];
        sig[4*i+0] = mk2(a.x, c.x); sig[4*i+1] = mk2(a.y, c.y);
        sig[4*i+2] = mk2(a.z, c.z); sig[4*i+3] = mk2(a.w, c.w);
    }
    #pragma unroll
    for (int i = 4; i < 8; ++i) {        // s=16..31 -> LDS (pairs)
        const float4 a = src[i];
        const float4 c = src[8 + i];
        sigh[2*(i-4)][tid]   = make_float4(a.x, c.x, a.y, c.y);
        sigh[2*(i-4)+1][tid] = make_float4(a.z, c.z, a.w, c.w);
        if (i == 7) {
            xty1 = a.w; xty2 = a.z;                 // own .x tail = .y raw history
            bnd[tid] = make_float2(c.w, c.z);       // thread raw tail (sample 63, 62)
        }
    }
    __syncthreads();

    v2f xw1, xw2;   // raw-x history per stream
    {
        float h1 = 0.f, h2 = 0.f;
        if (tid > 0) { const float2 t = bnd[tid-1]; h1 = t.x; h2 = t.y; }
        xw1 = mk2(h1, xty1);
        xw2 = mk2(h2, xty2);
    }

    v2f i1 = mk2(0.f,0.f), i2 = mk2(0.f,0.f);
    float pa1 = 0.f, pa2 = 0.f;

    #pragma unroll 1
    for (int j = 0; j < NFILT; ++j) {
        const float* cj = wsb + j*8;
        const float b0 = cj[0], b1c = cj[1], b2 = cj[2], a1 = cj[3], a2 = cj[4];
        const float* mb = wsb + MATS_OFF + j*44;
        const v2f nb0 = fs(b0), nb1 = fs(b1c), nb2 = fs(b2);
        const v2f na1 = fs(-a1), na2 = fs(-a2);
        const v2f np1 = fs(-pa1), np2 = fs(-pa2);

        // ---- fused elementwise: finalize(j-1) + FIR(j) + zero-init(j) ----
        v2f u1, u2, z1 = mk2(0.f,0.f), z2 = mk2(0.f,0.f);
        if (j == 0) { u1 = xw1; u2 = xw2; } else { u1 = i1; u2 = i2; }

        if (j == 0) {
            #pragma unroll
            for (int t = 0; t < 16; ++t) {
                const v2f u = sig[t];
                const v2f c = F2(nb0, u, F2(nb1, u1, nb2*u2));
                const v2f z = F2(na1, z1, F2(na2, z2, c));
                sig[t] = c; u2 = u1; u1 = u; z2 = z1; z1 = z;
            }
            #pragma unroll
            for (int i = 0; i < 8; ++i) {
                const float4 v = sigh[i][tid];
                v2f p = mk2(v.x, v.y), q = mk2(v.z, v.w);
                {
                    const v2f u = p;
                    const v2f c = F2(nb0, u, F2(nb1, u1, nb2*u2));
                    const v2f z = F2(na1, z1, F2(na2, z2, c));
                    p = c; u2 = u1; u1 = u; z2 = z1; z1 = z;
                }
                {
                    const v2f u = q;
                    const v2f c = F2(nb0, u, F2(nb1, u1, nb2*u2));
                    const v2f z = F2(na1, z1, F2(na2, z2, c));
                    q = c; u2 = u1; u1 = u; z2 = z1; z1 = z;
                }
                sigh[i][tid] = make_float4(p.x, p.y, q.x, q.y);
            }
        } else {
            #pragma unroll
            for (int t = 0; t < 16; ++t) {
                const v2f u = F2(np1, u1, F2(np2, u2, sig[t]));
                const v2f c = F2(nb0, u, F2(nb1, u1, nb2*u2));
                const v2f z = F2(na1, z1, F2(na2, z2, c));
                sig[t] = c; u2 = u1; u1 = u; z2 = z1; z1 = z;
            }
            #pragma unroll
            for (int i = 0; i < 8; ++i) {
                const float4 v = sigh[i][tid];
                v2f p = mk2(v.x, v.y), q = mk2(v.z, v.w);
                {
                    const v2f u = F2(np1, u1, F2(np2, u2, p));
                    const v2f c = F2(nb0, u, F2(nb1, u1, nb2*u2));
                    const v2f z = F2(na1, z1, F2(na2, z2, c));
                    p = c; u2 = u1; u1 = u; z2 = z1; z1 = z;
                }
                {
                    const v2f u = F2(np1, u1, F2(np2, u2, q));
                    const v2f c = F2(nb0, u, F2(nb1, u1, nb2*u2));
                    const v2f z = F2(na1, z1, F2(na2, z2, c));
                    q = c; u2 = u1; u1 = u; z2 = z1; z1 = z;
                }
                sigh[i][tid] = make_float4(p.x, p.y, q.x, q.y);
            }
        }

        // ---- thread particular over 64 samples: P = C^32 * z_x + z_y (scalar) ----
        const float4 M32 = *reinterpret_cast<const float4*>(mb + 10*4);
        float Sa = M32.x * z1.x + M32.y * z2.x + z1.y;
        float Sb = M32.z * z1.x + M32.w * z2.x + z2.y;

        // ---- in-wave inclusive affine scan (scalar, C^(64*2^r)) ----
        #pragma unroll
        for (int r = 0; r < 6; ++r) {
            const int d = 1 << r;
            const float4 M = *reinterpret_cast<const float4*>(mb + r*4);
            float ta = __shfl_up(Sa, d, 64);
            float tb = __shfl_up(Sb, d, 64);
            const bool act = (lane >= d);
            ta = act ? ta : 0.f;
            tb = act ? tb : 0.f;
            Sa = Sa + M.x * ta + M.y * tb;
            Sb = Sb + M.z * ta + M.w * tb;
        }
        const int buf = j & 1;
        if (lane == 63) waveP[buf][wid] = make_float2(Sa, Sb);
        __syncthreads();

        // ---- cross-wave: 4-level KS over 16 wave totals (lane space) ----
        const float2 Pv = waveP[buf][lane & 15];
        float Tx = Pv.x, Ty = Pv.y;
        #pragma unroll
        for (int l = 0; l < 4; ++l) {
            const int d = 1 << l;
            const float4 M = *reinterpret_cast<const float4*>(mb + (6+l)*4);
            float tx = __shfl_up(Tx, d, 64);
            float ty = __shfl_up(Ty, d, 64);
            const bool act = (lane >= d);
            tx = act ? tx : 0.f;
            ty = act ? ty : 0.f;
            Tx = Tx + M.x * tx + M.y * ty;
            Ty = Ty + M.z * tx + M.w * ty;
        }
        float Vx = __shfl(Tx, wid - 1, 64);
        float Vy = __shfl(Ty, wid - 1, 64);
        if (wid == 0) { Vx = 0.f; Vy = 0.f; }
        #pragma unroll
        for (int r = 0; r < 6; ++r) {      // apply C^(64*lane)
            const float4 M = *reinterpret_cast<const float4*>(mb + r*4);
            const bool bit = (lane >> r) & 1;
            const float nx = M.x * Vx + M.y * Vy;
            const float ny = M.z * Vx + M.w * Vy;
            Vx = bit ? nx : Vx;
            Vy = bit ? ny : Vy;
        }
        {   // + exclusive in-thread-space particular prefix
            float Ea = __shfl_up(Sa, 1, 64);
            float Eb = __shfl_up(Sb, 1, 64);
            const bool l0 = (lane == 0);
            Vx += l0 ? 0.f : Ea;
            Vy += l0 ? 0.f : Eb;
        }

        // ---- per-stream incoming states: .x gets V; .y gets C^32*V + z_x ----
        const float iy1 = M32.x * Vx + M32.y * Vy + z1.x;
        const float iy2 = M32.z * Vx + M32.w * Vy + z2.x;
        i1 = mk2(Vx, iy1);
        i2 = mk2(Vy, iy2);
        pa1 = a1; pa2 = a2;
    }

    // ---- tail: finalize filter 9; STRICTLY SEQUENTIAL stores per thread ----
    {
        v2f u1 = i1, u2 = i2;
        const v2f np1 = fs(-pa1), np2 = fs(-pa2);
        float4* d0 = reinterpret_cast<float4*>(ob + (size_t)tid * CHUNK);        // samples 0..31
        float4* d1 = reinterpret_cast<float4*>(ob + (size_t)tid * CHUNK + 32);   // samples 32..63
        float4 c4[4];                                  // .y results of sig phase

        // phase 1: sig (s=0..15) -> d0[0..3] sequential; .y held in regs
        #pragma unroll
        for (int i = 0; i < 4; ++i) {
            float4 a, c;
            #pragma unroll
            for (int e = 0; e < 4; ++e) {
                const v2f u = F2(np1, u1, F2(np2, u2, sig[4*i+e]));
                (&a.x)[e] = u.x; (&c.x)[e] = u.y;
                u2 = u1; u1 = u;
            }
            d0[i] = a;
            c4[i] = c;
        }
        // phase 2: sigh (s=16..31) -> d0[4..7] sequential; .y stashed into sigh rows
        #pragma unroll
        for (int i = 0; i < 4; ++i) {
            const float4 v = sigh[2*i][tid], w = sigh[2*i+1][tid];
            const v2f s0v = mk2(v.x, v.y), s1v = mk2(v.z, v.w);
            const v2f s2v = mk2(w.x, w.y), s3v = mk2(w.z, w.w);
            float4 a, c;
            v2f u;
            u = F2(np1, u1, F2(np2, u2, s0v)); a.x = u.x; c.x = u.y; u2 = u1; u1 = u;
            u = F2(np1, u1, F2(np2, u2, s1v)); a.y = u.x; c.y = u.y; u2 = u1; u1 = u;
            u = F2(np1, u1, F2(np2, u2, s2v)); a.z = u.x; c.z = u.y; u2 = u1; u1 = u;
            u = F2(np1, u1, F2(np2, u2, s3v)); a.w = u.x; c.w = u.y; u2 = u1; u1 = u;
            d0[4+i] = a;
            sigh[2*i][tid] = c;                        // row 2i already consumed
        }
        // phase 3: d1[0..7] sequential
        #pragma unroll
        for (int i = 0; i < 4; ++i) d1[i] = c4[i];
        #pragma unroll
        for (int i = 0; i < 4; ++i) d1[4+i] = sigh[2*i][tid];
    }
}

extern "C" void kernel_launch(void* const* d_in, const int* in_sizes, int n_in,
                              void* d_out, int out_size, void* d_ws, size_t ws_size,
                              hipStream_t stream) {
    const float* x    = (const float*)d_in[0];
    const float* w0   = (const float*)d_in[1];
    const float* qinv = (const float*)d_in[2];
    const float* gain = (const float*)d_in[3];
    float* out = (float*)d_out;
    float* ws  = (float*)d_ws;   // 256 * 576 * 4 B = 576 KiB

    const int B = in_sizes[1] / NFILT;   // 256 batches
    eq_precompute_kernel<<<B, 64, 0, stream>>>(w0, qinv, gain, ws);
    eq_cascade_kernel<<<B, THREADS, 0, stream>>>(x, out, ws);
}